// Round 5
// baseline (439.287 us; speedup 1.0000x reference)
//
#include <hip/hip_runtime.h>
#include <stdint.h>

typedef unsigned short u16;
typedef __attribute__((ext_vector_type(8))) __bf16 bf16x8;
typedef __attribute__((ext_vector_type(4))) float f32x4;

// ---------- helpers ----------
__device__ __forceinline__ u16 f2bf(float f) {  // RNE fp32 -> bf16
  unsigned int u = __builtin_bit_cast(unsigned int, f);
  u = (u + 0x7FFFu + ((u >> 16) & 1u)) >> 16;
  return (u16)u;
}
__device__ __forceinline__ u16 tern2bf(int s) {
  return s == 0 ? (u16)0 : (s > 0 ? (u16)0x3F80 : (u16)0xBF80);
}

#define GLOAD_LDS16(g, l)                                                          \
  __builtin_amdgcn_global_load_lds((__attribute__((address_space(1))) void*)(g),   \
                                   (__attribute__((address_space(3))) void*)(l),   \
                                   16, 0, 0)

// ---------- problem sizes ----------
#define M_TOK 8192
#define N_OUT 4096
#define K_IN  4096
#define RANK  32

// ---------- ws layout (bytes) ----------
#define WS_XB    0ull
#define WS_WB    67108864ull
#define WS_BB    100663296ull
#define WS_A32   100925440ull
#define WS_T32   101187584ull
#define WS_TPART 101711872ull
#define WS_FLAG  110100480ull

// ---------- prep kernels ----------
__global__ void k_convert_x(const float4* __restrict__ x, ushort4* __restrict__ xb, int n4) {
  int stride = gridDim.x * blockDim.x;
  for (int i = blockIdx.x * blockDim.x + threadIdx.x; i < n4; i += stride) {
    float4 v = x[i];
    ushort4 o;
    o.x = f2bf(v.x); o.y = f2bf(v.y); o.z = f2bf(v.z); o.w = f2bf(v.w);
    xb[i] = o;
  }
}

__global__ void k_detect_wtype(const int* __restrict__ w, int* __restrict__ flag) {
  int v = w[threadIdx.x];
  bool ok = (v >= -1 && v <= 1);
  unsigned long long m = __ballot(ok);
  if (threadIdx.x == 0) *flag = (m == ~0ull) ? 1 : 0;
}

__global__ void k_convert_w(const void* __restrict__ wq, const int* __restrict__ flag,
                            ushort4* __restrict__ wb, int n4) {
  int is32 = *flag;
  int stride = gridDim.x * blockDim.x;
  for (int i = blockIdx.x * blockDim.x + threadIdx.x; i < n4; i += stride) {
    int s0, s1, s2, s3;
    if (is32) {
      int4 c = ((const int4*)wq)[i];
      s0 = c.x; s1 = c.y; s2 = c.z; s3 = c.w;
    } else {
      char4 c = ((const char4*)wq)[i];
      s0 = c.x; s1 = c.y; s2 = c.z; s3 = c.w;
    }
    ushort4 o;
    o.x = tern2bf(s0); o.y = tern2bf(s1); o.z = tern2bf(s2); o.w = tern2bf(s3);
    wb[i] = o;
  }
}

__global__ void k_prep_B(const float* __restrict__ loraB, u16* __restrict__ bb) {
  int idx = blockIdx.x * blockDim.x + threadIdx.x;
  if (idx < RANK * K_IN) bb[idx] = f2bf(loraB[idx]);
}

__global__ void k_prep_A(const float* __restrict__ loraA, const float* __restrict__ scale,
                         u16* __restrict__ a32) {
  int idx = blockIdx.x * blockDim.x + threadIdx.x;
  if (idx >= N_OUT * RANK) return;
  int o = idx >> 5;
  a32[idx] = f2bf(loraA[idx] / scale[o]);
}

// ---------- T = x @ B^T (partials over 8 K-slices) ----------
__global__ __launch_bounds__(256) void k_lora_T(const u16* __restrict__ xb,
                                                const u16* __restrict__ bb,
                                                float* __restrict__ tpart) {
  __shared__ u16 As[256 * 32];
  __shared__ u16 Bs[32 * 32];
  int mt = blockIdx.x >> 3;
  int ks = blockIdx.x & 7;
  int tid = threadIdx.x, lane = tid & 63, wave = tid >> 6;
  int m0 = mt * 256;
  int kbase0 = ks * 512;
  f32x4 acc[4][2] = {};
  for (int step = 0; step < 16; ++step) {
    int kb = kbase0 + step * 32;
    __syncthreads();
#pragma unroll
    for (int i = 0; i < 4; ++i) {
      const u16* src = xb + (size_t)(m0 + i * 64 + (tid >> 2)) * K_IN + kb + (tid & 3) * 8;
      GLOAD_LDS16(src, &As[i * 2048 + tid * 8]);
    }
    if (tid < 128) {
      const u16* src = bb + (size_t)(tid >> 2) * K_IN + kb + (tid & 3) * 8;
      GLOAD_LDS16(src, &Bs[tid * 8]);
    }
    __syncthreads();
    bf16x8 b[2];
#pragma unroll
    for (int ni = 0; ni < 2; ++ni)
      b[ni] = *(const bf16x8*)&Bs[(ni * 16 + (lane & 15)) * 32 + (lane >> 4) * 8];
#pragma unroll
    for (int mi = 0; mi < 4; ++mi) {
      bf16x8 a = *(const bf16x8*)&As[(wave * 64 + mi * 16 + (lane & 15)) * 32 + (lane >> 4) * 8];
      acc[mi][0] = __builtin_amdgcn_mfma_f32_16x16x32_bf16(a, b[0], acc[mi][0], 0, 0, 0);
      acc[mi][1] = __builtin_amdgcn_mfma_f32_16x16x32_bf16(a, b[1], acc[mi][1], 0, 0, 0);
    }
  }
#pragma unroll
  for (int mi = 0; mi < 4; ++mi)
#pragma unroll
    for (int ni = 0; ni < 2; ++ni)
#pragma unroll
      for (int r = 0; r < 4; ++r) {
        int row = m0 + wave * 64 + mi * 16 + (lane >> 4) * 4 + r;
        int col = ni * 16 + (lane & 15);
        tpart[((size_t)ks * M_TOK + row) * RANK + col] = acc[mi][ni][r];
      }
}

__global__ void k_reduce_T(const float* __restrict__ tpart, u16* __restrict__ t32) {
  int idx = blockIdx.x * blockDim.x + threadIdx.x;
  if (idx >= M_TOK * RANK) return;
  int t = idx >> 5, r = idx & 31;
  float v = 0.f;
#pragma unroll
  for (int s = 0; s < 8; ++s) v += tpart[((size_t)s * M_TOK + t) * RANK + r];
  t32[idx] = f2bf(v);
}

// ---------- main GEMM: 256x256 tile, BK=32, A via ring-4 LDS, B direct->regs ----------
// B (W) fragments are loaded straight from global (L2-resident, naturally
// coalesced 16rows x 64B) into a ping-pong register pair one tile ahead;
// LDS holds only A (x) tiles: ring-4 x 16KB, staged 3 ahead via gload_lds
// with the R2/R4-verified 0-conflict swizzle. 1 barrier + 1 counted vmcnt
// per tile. A-wait: 6 vm-ops/tile, A(t+1) issued at t-2 -> vmcnt(12).
__global__ __launch_bounds__(512, 2) void k_gemm8(const u16* __restrict__ xb,
                                                  const u16* __restrict__ wb,
                                                  const u16* __restrict__ t32,
                                                  const u16* __restrict__ a32,
                                                  const float* __restrict__ scale,
                                                  const float* __restrict__ bias,
                                                  float* __restrict__ out) {
  __shared__ u16 As[4][8192];  // 4 slots x 16KB (A only)
  const int tid = threadIdx.x;
  const int l = tid & 63, w = tid >> 6;
  const int wm = w >> 2, wn = w & 3;
  const int bid = blockIdx.x;
  const int swz = (bid & 7) * 64 + (bid >> 3);
  const int m0 = (swz >> 4) * 256, n0 = (swz & 15) * 256;

  const int srow0 = (w * 2 + 0) * 16 + (l >> 2);
  const int srow1 = (w * 2 + 1) * 16 + (l >> 2);
  const int scx = ((l & 3) ^ ((l >> 3) & 3)) * 8;
  const int ldst0 = (w * 2 + 0) * 512 + l * 8;
  const int ldst1 = (w * 2 + 1) * 512 + l * 8;
  const int r15 = l & 15;
  const int cxr = (((l >> 4) ^ ((r15 >> 1) & 3)) * 8);

  f32x4 acc[8][4] = {};

  u16* AsF = &As[0][0];
  const u16* axs0 = xb + (size_t)(m0 + srow0) * K_IN + scx;
  const u16* axs1 = xb + (size_t)(m0 + srow1) * K_IN + scx;

  // B row pointers (canonical frag layout: row = wn*64+nj*16+r15, k-chunk (l>>4)*8)
  const u16* wrowp[4];
#pragma unroll
  for (int nj = 0; nj < 4; ++nj)
    wrowp[nj] = wb + (size_t)(n0 + wn * 64 + nj * 16 + r15) * K_IN + (l >> 4) * 8;
  const u16* arowp[4];
#pragma unroll
  for (int nj = 0; nj < 4; ++nj)
    arowp[nj] = a32 + (size_t)(n0 + wn * 64 + nj * 16 + r15) * RANK + (l >> 4) * 8;

  bf16x8 bA[4], bB[4];

  // prologue: stage A tiles 0,1,2; load B(0) into bA
#pragma unroll
  for (int ts = 0; ts < 3; ++ts) {
    GLOAD_LDS16(axs0 + ts * 32, AsF + ts * 8192 + ldst0);
    GLOAD_LDS16(axs1 + ts * 32, AsF + ts * 8192 + ldst1);
  }
#pragma unroll
  for (int nj = 0; nj < 4; ++nj) { bA[nj] = *(const bf16x8*)(wrowp[nj]); wrowp[nj] += 32; }
  asm volatile("s_waitcnt vmcnt(4)" ::: "memory");
  asm volatile("s_barrier" ::: "memory");

  const int abase = (wm * 128 + r15) * 32 + cxr;

  // running A-stage pointers -> tile 3
  const u16* ap0 = axs0 + 96;
  const u16* ap1 = axs1 + 96;

#define SA(DST)                                                                     \
  { GLOAD_LDS16(ap0, AsF + (DST) * 8192 + ldst0);                                   \
    GLOAD_LDS16(ap1, AsF + (DST) * 8192 + ldst1);                                   \
    ap0 += 32; ap1 += 32; }
#define LOADB_W(BN)                                                                 \
  { _Pragma("unroll") for (int nj = 0; nj < 4; ++nj) {                              \
      BN[nj] = *(const bf16x8*)(wrowp[nj]); wrowp[nj] += 32; } }
#define LOADB_L(BN)                                                                 \
  { _Pragma("unroll") for (int nj = 0; nj < 4; ++nj) BN[nj] = *(const bf16x8*)(arowp[nj]); }
#define W12 asm volatile("s_waitcnt vmcnt(12)" ::: "memory");
#define W10 asm volatile("s_waitcnt vmcnt(10)" ::: "memory");
#define W8  asm volatile("s_waitcnt vmcnt(8)" ::: "memory");
#define BARR asm volatile("s_barrier" ::: "memory");

#define TILE(SLOT, BC, LOADB, STAGE, WAIT, BAR)                                     \
  {                                                                                 \
    const u16* Asl = AsF + (SLOT) * 8192;                                           \
    bf16x8 a0[4], a1[4];                                                            \
    _Pragma("unroll") for (int mi = 0; mi < 4; ++mi)                                \
        a0[mi] = *(const bf16x8*)&Asl[abase + mi * 512];                            \
    LOADB                                                                           \
    STAGE                                                                           \
    __builtin_amdgcn_s_setprio(1);                                                  \
    _Pragma("unroll") for (int mi = 0; mi < 4; ++mi)                                \
    _Pragma("unroll") for (int nj = 0; nj < 4; ++nj)                                \
        acc[mi][nj] =                                                               \
            __builtin_amdgcn_mfma_f32_16x16x32_bf16(a0[mi], BC[nj], acc[mi][nj], 0, 0, 0); \
    __builtin_amdgcn_s_setprio(0);                                                  \
    _Pragma("unroll") for (int mi = 0; mi < 4; ++mi)                                \
        a1[mi] = *(const bf16x8*)&Asl[abase + 2048 + mi * 512];                     \
    __builtin_amdgcn_s_setprio(1);                                                  \
    _Pragma("unroll") for (int mi = 0; mi < 4; ++mi)                                \
    _Pragma("unroll") for (int nj = 0; nj < 4; ++nj)                                \
        acc[4 + mi][nj] =                                                           \
            __builtin_amdgcn_mfma_f32_16x16x32_bf16(a1[mi], BC[nj], acc[4 + mi][nj], 0, 0, 0); \
    __builtin_amdgcn_s_setprio(0);                                                  \
    WAIT                                                                            \
    BAR                                                                             \
  }

  // main loop: tiles 0..123 (B parity: even->consume bA, load bB)
#pragma unroll 1
  for (int t = 0; t < 124; t += 4) {
    TILE(0, bA, LOADB_W(bB), SA(3), W12, BARR)
    TILE(1, bB, LOADB_W(bA), SA(0), W12, BARR)
    TILE(2, bA, LOADB_W(bB), SA(1), W12, BARR)
    TILE(3, bB, LOADB_W(bA), SA(2), W12, BARR)
  }
  // t=124: stage A tile 127 -> slot 3
  TILE(0, bA, LOADB_W(bB), SA(3), W12, BARR)
  // t=125: stage LoRA A-tile (t32) -> slot 0
  {
    const u16* la0 = t32 + (size_t)(m0 + srow0) * RANK + scx;
    const u16* la1 = t32 + (size_t)(m0 + srow1) * RANK + scx;
    TILE(1, bB, LOADB_W(bA),
         { GLOAD_LDS16(la0, AsF + 0 * 8192 + ldst0); GLOAD_LDS16(la1, AsF + 0 * 8192 + ldst1); },
         W12, BARR)
  }
  // t=126: load B(127); t=127: load LoRA B (a32) into bA; t=128: LoRA tile
  TILE(2, bA, LOADB_W(bB), , W10, BARR)
  TILE(3, bB, LOADB_L(bA), , W8, BARR)
  TILE(0, bA, , , , )

  // epilogue: out = acc*scale[col] + bias[col]
#pragma unroll
  for (int nj = 0; nj < 4; ++nj) {
    int col = n0 + wn * 64 + nj * 16 + r15;
    float s = scale[col], bv = bias[col];
#pragma unroll
    for (int fi = 0; fi < 8; ++fi) {
      int row = m0 + wm * 128 + (fi >> 2) * 64 + (fi & 3) * 16 + (l >> 4) * 4;
#pragma unroll
      for (int r = 0; r < 4; ++r)
        out[(size_t)(row + r) * N_OUT + col] = acc[fi][nj][r] * s + bv;
    }
  }
}

// ---------- launch ----------
extern "C" void kernel_launch(void* const* d_in, const int* in_sizes, int n_in,
                              void* d_out, int out_size, void* d_ws, size_t ws_size,
                              hipStream_t stream) {
  const float* x     = (const float*)d_in[0];
  const void*  wq    = d_in[1];
  const float* scale = (const float*)d_in[2];
  const float* loraA = (const float*)d_in[3];
  const float* loraB = (const float*)d_in[4];
  const float* bias  = (const float*)d_in[5];
  float* out = (float*)d_out;

  char* ws = (char*)d_ws;
  u16*   xb    = (u16*)(ws + WS_XB);
  u16*   wbuf  = (u16*)(ws + WS_WB);
  u16*   bb    = (u16*)(ws + WS_BB);
  u16*   a32   = (u16*)(ws + WS_A32);
  u16*   t32   = (u16*)(ws + WS_T32);
  float* tpart = (float*)(ws + WS_TPART);
  int*   flag  = (int*)(ws + WS_FLAG);

  k_convert_x<<<2048, 256, 0, stream>>>((const float4*)x, (ushort4*)xb, M_TOK * K_IN / 4);
  k_detect_wtype<<<1, 64, 0, stream>>>((const int*)wq, flag);
  k_convert_w<<<2048, 256, 0, stream>>>(wq, flag, (ushort4*)wbuf, N_OUT * K_IN / 4);
  k_prep_B<<<512, 256, 0, stream>>>(loraB, bb);
  k_prep_A<<<512, 256, 0, stream>>>(loraA, scale, a32);
  k_lora_T<<<256, 256, 0, stream>>>(xb, bb, tpart);
  k_reduce_T<<<1024, 256, 0, stream>>>(tpart, t32);
  k_gemm8<<<512, 512, 0, stream>>>(xb, wbuf, t32, a32, scale, bias, out);

  (void)in_sizes; (void)n_in; (void)out_size; (void)ws_size;
}

// Round 6
// 323.345 us; speedup vs baseline: 1.3586x; 1.3586x over previous
//
#include <hip/hip_runtime.h>
#include <stdint.h>

typedef unsigned short u16;
typedef __attribute__((ext_vector_type(8))) __bf16 bf16x8;
typedef __attribute__((ext_vector_type(4))) float f32x4;

// ---------- helpers ----------
__device__ __forceinline__ u16 f2bf(float f) {  // RNE fp32 -> bf16
  unsigned int u = __builtin_bit_cast(unsigned int, f);
  u = (u + 0x7FFFu + ((u >> 16) & 1u)) >> 16;
  return (u16)u;
}
__device__ __forceinline__ u16 tern2bf(int s) {
  return s == 0 ? (u16)0 : (s > 0 ? (u16)0x3F80 : (u16)0xBF80);
}

#define GLOAD_LDS16(g, l)                                                          \
  __builtin_amdgcn_global_load_lds((__attribute__((address_space(1))) void*)(g),   \
                                   (__attribute__((address_space(3))) void*)(l),   \
                                   16, 0, 0)

// ---------- problem sizes ----------
#define M_TOK 8192
#define N_OUT 4096
#define K_IN  4096
#define RANK  32

// ---------- ws layout (bytes) ----------
#define WS_XB    0ull
#define WS_WB    67108864ull
#define WS_BB    100663296ull
#define WS_A32   100925440ull
#define WS_T32   101187584ull
#define WS_TPART 101711872ull
#define WS_FLAG  110100480ull

// ---------- prep kernels ----------
__global__ void k_convert_x(const float4* __restrict__ x, ushort4* __restrict__ xb, int n4) {
  int stride = gridDim.x * blockDim.x;
  for (int i = blockIdx.x * blockDim.x + threadIdx.x; i < n4; i += stride) {
    float4 v = x[i];
    ushort4 o;
    o.x = f2bf(v.x); o.y = f2bf(v.y); o.z = f2bf(v.z); o.w = f2bf(v.w);
    xb[i] = o;
  }
}

__global__ void k_detect_wtype(const int* __restrict__ w, int* __restrict__ flag) {
  int v = w[threadIdx.x];
  bool ok = (v >= -1 && v <= 1);
  unsigned long long m = __ballot(ok);
  if (threadIdx.x == 0) *flag = (m == ~0ull) ? 1 : 0;
}

__global__ void k_convert_w(const void* __restrict__ wq, const int* __restrict__ flag,
                            ushort4* __restrict__ wb, int n4) {
  int is32 = *flag;
  int stride = gridDim.x * blockDim.x;
  for (int i = blockIdx.x * blockDim.x + threadIdx.x; i < n4; i += stride) {
    int s0, s1, s2, s3;
    if (is32) {
      int4 c = ((const int4*)wq)[i];
      s0 = c.x; s1 = c.y; s2 = c.z; s3 = c.w;
    } else {
      char4 c = ((const char4*)wq)[i];
      s0 = c.x; s1 = c.y; s2 = c.z; s3 = c.w;
    }
    ushort4 o;
    o.x = tern2bf(s0); o.y = tern2bf(s1); o.z = tern2bf(s2); o.w = tern2bf(s3);
    wb[i] = o;
  }
}

__global__ void k_prep_B(const float* __restrict__ loraB, u16* __restrict__ bb) {
  int idx = blockIdx.x * blockDim.x + threadIdx.x;
  if (idx < RANK * K_IN) bb[idx] = f2bf(loraB[idx]);
}

__global__ void k_prep_A(const float* __restrict__ loraA, const float* __restrict__ scale,
                         u16* __restrict__ a32) {
  int idx = blockIdx.x * blockDim.x + threadIdx.x;
  if (idx >= N_OUT * RANK) return;
  int o = idx >> 5;
  a32[idx] = f2bf(loraA[idx] / scale[o]);
}

// ---------- T = x @ B^T (partials over 8 K-slices) ----------
__global__ __launch_bounds__(256) void k_lora_T(const u16* __restrict__ xb,
                                                const u16* __restrict__ bb,
                                                float* __restrict__ tpart) {
  __shared__ u16 As[256 * 32];
  __shared__ u16 Bs[32 * 32];
  int mt = blockIdx.x >> 3;
  int ks = blockIdx.x & 7;
  int tid = threadIdx.x, lane = tid & 63, wave = tid >> 6;
  int m0 = mt * 256;
  int kbase0 = ks * 512;
  f32x4 acc[4][2] = {};
  for (int step = 0; step < 16; ++step) {
    int kb = kbase0 + step * 32;
    __syncthreads();
#pragma unroll
    for (int i = 0; i < 4; ++i) {
      const u16* src = xb + (size_t)(m0 + i * 64 + (tid >> 2)) * K_IN + kb + (tid & 3) * 8;
      GLOAD_LDS16(src, &As[i * 2048 + tid * 8]);
    }
    if (tid < 128) {
      const u16* src = bb + (size_t)(tid >> 2) * K_IN + kb + (tid & 3) * 8;
      GLOAD_LDS16(src, &Bs[tid * 8]);
    }
    __syncthreads();
    bf16x8 b[2];
#pragma unroll
    for (int ni = 0; ni < 2; ++ni)
      b[ni] = *(const bf16x8*)&Bs[(ni * 16 + (lane & 15)) * 32 + (lane >> 4) * 8];
#pragma unroll
    for (int mi = 0; mi < 4; ++mi) {
      bf16x8 a = *(const bf16x8*)&As[(wave * 64 + mi * 16 + (lane & 15)) * 32 + (lane >> 4) * 8];
      acc[mi][0] = __builtin_amdgcn_mfma_f32_16x16x32_bf16(a, b[0], acc[mi][0], 0, 0, 0);
      acc[mi][1] = __builtin_amdgcn_mfma_f32_16x16x32_bf16(a, b[1], acc[mi][1], 0, 0, 0);
    }
  }
#pragma unroll
  for (int mi = 0; mi < 4; ++mi)
#pragma unroll
    for (int ni = 0; ni < 2; ++ni)
#pragma unroll
      for (int r = 0; r < 4; ++r) {
        int row = m0 + wave * 64 + mi * 16 + (lane >> 4) * 4 + r;
        int col = ni * 16 + (lane & 15);
        tpart[((size_t)ks * M_TOK + row) * RANK + col] = acc[mi][ni][r];
      }
}

__global__ void k_reduce_T(const float* __restrict__ tpart, u16* __restrict__ t32) {
  int idx = blockIdx.x * blockDim.x + threadIdx.x;
  if (idx >= M_TOK * RANK) return;
  int t = idx >> 5, r = idx & 31;
  float v = 0.f;
#pragma unroll
  for (int s = 0; s < 8; ++s) v += tpart[((size_t)s * M_TOK + t) * RANK + r];
  t32[idx] = f2bf(v);
}

// ---------- main GEMM: 256x256, BK=32, ring-4 LDS, frag read-ahead ----------
// R4 skeleton (A+B in LDS, 0-conflict swizzle, 1 barrier/tile) plus:
// next tile's phase-0 A/B fragments are read into registers at the END of
// the current tile (after WAIT, before BAR), so every tile opens with MFMA.
// Steady wait strengthened W8->W4: at tile t-1 each wave's vmcnt(4) leaves
// only stage(t+2) outstanding => tiles <= t+1 landed; BAR(t-1) makes that a
// cross-wave guarantee, so pre-BAR reads of slot t+1 during tile t are
// race-free by construction. Tail waits: W4, W4, W0, none.
__global__ __launch_bounds__(512, 2) void k_gemm8(const u16* __restrict__ xb,
                                                  const u16* __restrict__ wb,
                                                  const u16* __restrict__ t32,
                                                  const u16* __restrict__ a32,
                                                  const float* __restrict__ scale,
                                                  const float* __restrict__ bias,
                                                  float* __restrict__ out) {
  __shared__ u16 As[4][8192];  // 4 slots x 16KB
  __shared__ u16 Bs[4][8192];
  const int tid = threadIdx.x;
  const int l = tid & 63, w = tid >> 6;
  const int wm = w >> 2, wn = w & 3;
  const int bid = blockIdx.x;
  const int swz = (bid & 7) * 64 + (bid >> 3);
  const int m0 = (swz >> 4) * 256, n0 = (swz & 15) * 256;

  const int srow0 = (w * 2 + 0) * 16 + (l >> 2);
  const int srow1 = (w * 2 + 1) * 16 + (l >> 2);
  const int scx = ((l & 3) ^ ((l >> 3) & 3)) * 8;
  const int ldst0 = (w * 2 + 0) * 512 + l * 8;
  const int ldst1 = (w * 2 + 1) * 512 + l * 8;
  const int r15 = l & 15;
  const int cxr = (((l >> 4) ^ ((r15 >> 1) & 3)) * 8);

  f32x4 acc[8][4] = {};

  u16* AsF = &As[0][0];
  u16* BsF = &Bs[0][0];
  const u16* axs0 = xb + (size_t)(m0 + srow0) * K_IN + scx;
  const u16* axs1 = xb + (size_t)(m0 + srow1) * K_IN + scx;
  const u16* bxs0 = wb + (size_t)(n0 + srow0) * K_IN + scx;
  const u16* bxs1 = wb + (size_t)(n0 + srow1) * K_IN + scx;

  // prologue: stage tiles 0,1,2
#pragma unroll
  for (int ts = 0; ts < 3; ++ts) {
    GLOAD_LDS16(axs0 + ts * 32, AsF + ts * 8192 + ldst0);
    GLOAD_LDS16(axs1 + ts * 32, AsF + ts * 8192 + ldst1);
    GLOAD_LDS16(bxs0 + ts * 32, BsF + ts * 8192 + ldst0);
    GLOAD_LDS16(bxs1 + ts * 32, BsF + ts * 8192 + ldst1);
  }
  asm volatile("s_waitcnt vmcnt(4)" ::: "memory");  // tiles 0,1 landed (this wave)
  asm volatile("s_barrier" ::: "memory");           // => landed cross-wave

  const int abase = (wm * 128 + r15) * 32 + cxr;
  const int bbase = (wn * 64 + r15) * 32 + cxr;

  // running stage pointers -> tile 3
  const u16* ap0 = axs0 + 96;
  const u16* ap1 = axs1 + 96;
  const u16* bp0 = bxs0 + 96;
  const u16* bp1 = bxs1 + 96;

#define SA(DST)                                                                     \
  { GLOAD_LDS16(ap0, AsF + (DST) * 8192 + ldst0);                                   \
    GLOAD_LDS16(ap1, AsF + (DST) * 8192 + ldst1);                                   \
    ap0 += 32; ap1 += 32; }
#define SB(DST)                                                                     \
  { GLOAD_LDS16(bp0, BsF + (DST) * 8192 + ldst0);                                   \
    GLOAD_LDS16(bp1, BsF + (DST) * 8192 + ldst1);                                   \
    bp0 += 32; bp1 += 32; }
#define W4  asm volatile("s_waitcnt vmcnt(4)" ::: "memory");
#define W0  asm volatile("s_waitcnt vmcnt(0)" ::: "memory");
#define BARR asm volatile("s_barrier" ::: "memory");
#define READN(NS, A0N, BN)                                                          \
  { const u16* An = AsF + (NS) * 8192;                                              \
    const u16* Bn = BsF + (NS) * 8192;                                              \
    _Pragma("unroll") for (int mi = 0; mi < 4; ++mi)                                \
        A0N[mi] = *(const bf16x8*)&An[abase + mi * 512];                            \
    _Pragma("unroll") for (int nj = 0; nj < 4; ++nj)                                \
        BN[nj] = *(const bf16x8*)&Bn[bbase + nj * 512]; }

// One tile: a1 reads + stages overlap MFMA0/MFMA1 (current frags preloaded);
// WAIT then next-tile frag reads, then trailing barrier.
#define TILE(SLOT, A0C, BC, STAGE_A, STAGE_B, WAIT, RD, BAR)                        \
  {                                                                                 \
    const u16* Asl = AsF + (SLOT) * 8192;                                           \
    bf16x8 a1[4];                                                                   \
    _Pragma("unroll") for (int mi = 0; mi < 4; ++mi)                                \
        a1[mi] = *(const bf16x8*)&Asl[abase + 2048 + mi * 512];                     \
    STAGE_A                                                                         \
    __builtin_amdgcn_s_setprio(1);                                                  \
    _Pragma("unroll") for (int mi = 0; mi < 4; ++mi)                                \
    _Pragma("unroll") for (int nj = 0; nj < 4; ++nj)                                \
        acc[mi][nj] =                                                               \
            __builtin_amdgcn_mfma_f32_16x16x32_bf16(A0C[mi], BC[nj], acc[mi][nj], 0, 0, 0); \
    __builtin_amdgcn_s_setprio(0);                                                  \
    STAGE_B                                                                         \
    __builtin_amdgcn_s_setprio(1);                                                  \
    _Pragma("unroll") for (int mi = 0; mi < 4; ++mi)                                \
    _Pragma("unroll") for (int nj = 0; nj < 4; ++nj)                                \
        acc[4 + mi][nj] =                                                           \
            __builtin_amdgcn_mfma_f32_16x16x32_bf16(a1[mi], BC[nj], acc[4 + mi][nj], 0, 0, 0); \
    __builtin_amdgcn_s_setprio(0);                                                  \
    WAIT                                                                            \
    RD                                                                              \
    BAR                                                                             \
  }

  bf16x8 a0e[4], be[4], a0o[4], bo[4];
  READN(0, a0e, be)  // tile 0 frags (post-barrier: globally landed)

  // main loop: tiles 0..123, staging 3..127
#pragma unroll 1
  for (int t = 0; t < 124; t += 4) {
    TILE(0, a0e, be, SA(3), SB(3), W4, READN(1, a0o, bo), BARR)
    TILE(1, a0o, bo, SA(0), SB(0), W4, READN(2, a0e, be), BARR)
    TILE(2, a0e, be, SA(1), SB(1), W4, READN(3, a0o, bo), BARR)
    TILE(3, a0o, bo, SA(2), SB(2), W4, READN(0, a0e, be), BARR)
  }
  // t=124 (slot0): stage tile 127 -> slot 3
  TILE(0, a0e, be, SA(3), SB(3), W4, READN(1, a0o, bo), BARR)
  // t=125 (slot1): stage LoRA tile (128) -> slot 0
  {
    const u16* la0 = t32 + (size_t)(m0 + srow0) * RANK + scx;
    const u16* la1 = t32 + (size_t)(m0 + srow1) * RANK + scx;
    const u16* lb0 = a32 + (size_t)(n0 + srow0) * RANK + scx;
    const u16* lb1 = a32 + (size_t)(n0 + srow1) * RANK + scx;
    TILE(1, a0o, bo,
         { GLOAD_LDS16(la0, AsF + 0 * 8192 + ldst0); GLOAD_LDS16(la1, AsF + 0 * 8192 + ldst1); },
         { GLOAD_LDS16(lb0, BsF + 0 * 8192 + ldst0); GLOAD_LDS16(lb1, BsF + 0 * 8192 + ldst1); },
         W4, READN(2, a0e, be), BARR)
  }
  // t=126 (slot2): full drain so LoRA slot is globally landed after BAR
  TILE(2, a0e, be, , , W0, READN(3, a0o, bo), BARR)
  // t=127 (slot3): nothing outstanding; pre-read LoRA frags
  TILE(3, a0o, bo, , , , READN(0, a0e, be), BARR)
  // t=128: LoRA tile (slot0), frags preloaded
  TILE(0, a0e, be, , , , , )

  // epilogue: out = acc*scale[col] + bias[col]
#pragma unroll
  for (int nj = 0; nj < 4; ++nj) {
    int col = n0 + wn * 64 + nj * 16 + r15;
    float s = scale[col], bv = bias[col];
#pragma unroll
    for (int fi = 0; fi < 8; ++fi) {
      int row = m0 + wm * 128 + (fi >> 2) * 64 + (fi & 3) * 16 + (l >> 4) * 4;
#pragma unroll
      for (int r = 0; r < 4; ++r)
        out[(size_t)(row + r) * N_OUT + col] = acc[fi][nj][r] * s + bv;
    }
  }
}

// ---------- launch ----------
extern "C" void kernel_launch(void* const* d_in, const int* in_sizes, int n_in,
                              void* d_out, int out_size, void* d_ws, size_t ws_size,
                              hipStream_t stream) {
  const float* x     = (const float*)d_in[0];
  const void*  wq    = d_in[1];
  const float* scale = (const float*)d_in[2];
  const float* loraA = (const float*)d_in[3];
  const float* loraB = (const float*)d_in[4];
  const float* bias  = (const float*)d_in[5];
  float* out = (float*)d_out;

  char* ws = (char*)d_ws;
  u16*   xb    = (u16*)(ws + WS_XB);
  u16*   wbuf  = (u16*)(ws + WS_WB);
  u16*   bb    = (u16*)(ws + WS_BB);
  u16*   a32   = (u16*)(ws + WS_A32);
  u16*   t32   = (u16*)(ws + WS_T32);
  float* tpart = (float*)(ws + WS_TPART);
  int*   flag  = (int*)(ws + WS_FLAG);

  k_convert_x<<<2048, 256, 0, stream>>>((const float4*)x, (ushort4*)xb, M_TOK * K_IN / 4);
  k_detect_wtype<<<1, 64, 0, stream>>>((const int*)wq, flag);
  k_convert_w<<<2048, 256, 0, stream>>>(wq, flag, (ushort4*)wbuf, N_OUT * K_IN / 4);
  k_prep_B<<<512, 256, 0, stream>>>(loraB, bb);
  k_prep_A<<<512, 256, 0, stream>>>(loraA, scale, a32);
  k_lora_T<<<256, 256, 0, stream>>>(xb, bb, tpart);
  k_reduce_T<<<1024, 256, 0, stream>>>(tpart, t32);
  k_gemm8<<<512, 512, 0, stream>>>(xb, wbuf, t32, a32, scale, bias, out);

  (void)in_sizes; (void)n_in; (void)out_size; (void)ws_size;
}

// Round 7
// 310.882 us; speedup vs baseline: 1.4130x; 1.0401x over previous
//
#include <hip/hip_runtime.h>
#include <stdint.h>

typedef unsigned short u16;
typedef __attribute__((ext_vector_type(8))) __bf16 bf16x8;
typedef __attribute__((ext_vector_type(4))) float f32x4;

// ---------- helpers ----------
__device__ __forceinline__ u16 f2bf(float f) {  // RNE fp32 -> bf16
  unsigned int u = __builtin_bit_cast(unsigned int, f);
  u = (u + 0x7FFFu + ((u >> 16) & 1u)) >> 16;
  return (u16)u;
}
__device__ __forceinline__ u16 tern2bf(int s) {
  return s == 0 ? (u16)0 : (s > 0 ? (u16)0x3F80 : (u16)0xBF80);
}

#define GLOAD_LDS16(g, l)                                                          \
  __builtin_amdgcn_global_load_lds((__attribute__((address_space(1))) void*)(g),   \
                                   (__attribute__((address_space(3))) void*)(l),   \
                                   16, 0, 0)

// ---------- problem sizes ----------
#define M_TOK 8192
#define N_OUT 4096
#define K_IN  4096
#define RANK  32

// ---------- ws layout (bytes) ----------
#define WS_XB    0ull
#define WS_WB    67108864ull
#define WS_BB    100663296ull
#define WS_A32   100925440ull
#define WS_T32   101187584ull
#define WS_TPART 101711872ull
#define WS_FLAG  110100480ull

// ---------- prep kernels ----------
__global__ void k_convert_x(const float4* __restrict__ x, ushort4* __restrict__ xb, int n4) {
  int stride = gridDim.x * blockDim.x;
  for (int i = blockIdx.x * blockDim.x + threadIdx.x; i < n4; i += stride) {
    float4 v = x[i];
    ushort4 o;
    o.x = f2bf(v.x); o.y = f2bf(v.y); o.z = f2bf(v.z); o.w = f2bf(v.w);
    xb[i] = o;
  }
}

__global__ void k_detect_wtype(const int* __restrict__ w, int* __restrict__ flag) {
  int v = w[threadIdx.x];
  bool ok = (v >= -1 && v <= 1);
  unsigned long long m = __ballot(ok);
  if (threadIdx.x == 0) *flag = (m == ~0ull) ? 1 : 0;
}

__global__ void k_convert_w(const void* __restrict__ wq, const int* __restrict__ flag,
                            ushort4* __restrict__ wb, int n4) {
  int is32 = *flag;
  int stride = gridDim.x * blockDim.x;
  for (int i = blockIdx.x * blockDim.x + threadIdx.x; i < n4; i += stride) {
    int s0, s1, s2, s3;
    if (is32) {
      int4 c = ((const int4*)wq)[i];
      s0 = c.x; s1 = c.y; s2 = c.z; s3 = c.w;
    } else {
      char4 c = ((const char4*)wq)[i];
      s0 = c.x; s1 = c.y; s2 = c.z; s3 = c.w;
    }
    ushort4 o;
    o.x = tern2bf(s0); o.y = tern2bf(s1); o.z = tern2bf(s2); o.w = tern2bf(s3);
    wb[i] = o;
  }
}

__global__ void k_prep_B(const float* __restrict__ loraB, u16* __restrict__ bb) {
  int idx = blockIdx.x * blockDim.x + threadIdx.x;
  if (idx < RANK * K_IN) bb[idx] = f2bf(loraB[idx]);
}

__global__ void k_prep_A(const float* __restrict__ loraA, const float* __restrict__ scale,
                         u16* __restrict__ a32) {
  int idx = blockIdx.x * blockDim.x + threadIdx.x;
  if (idx >= N_OUT * RANK) return;
  int o = idx >> 5;
  a32[idx] = f2bf(loraA[idx] / scale[o]);
}

// ---------- T = x @ B^T (partials over 8 K-slices) ----------
__global__ __launch_bounds__(256) void k_lora_T(const u16* __restrict__ xb,
                                                const u16* __restrict__ bb,
                                                float* __restrict__ tpart) {
  __shared__ u16 As[256 * 32];
  __shared__ u16 Bs[32 * 32];
  int mt = blockIdx.x >> 3;
  int ks = blockIdx.x & 7;
  int tid = threadIdx.x, lane = tid & 63, wave = tid >> 6;
  int m0 = mt * 256;
  int kbase0 = ks * 512;
  f32x4 acc[4][2] = {};
  for (int step = 0; step < 16; ++step) {
    int kb = kbase0 + step * 32;
    __syncthreads();
#pragma unroll
    for (int i = 0; i < 4; ++i) {
      const u16* src = xb + (size_t)(m0 + i * 64 + (tid >> 2)) * K_IN + kb + (tid & 3) * 8;
      GLOAD_LDS16(src, &As[i * 2048 + tid * 8]);
    }
    if (tid < 128) {
      const u16* src = bb + (size_t)(tid >> 2) * K_IN + kb + (tid & 3) * 8;
      GLOAD_LDS16(src, &Bs[tid * 8]);
    }
    __syncthreads();
    bf16x8 b[2];
#pragma unroll
    for (int ni = 0; ni < 2; ++ni)
      b[ni] = *(const bf16x8*)&Bs[(ni * 16 + (lane & 15)) * 32 + (lane >> 4) * 8];
#pragma unroll
    for (int mi = 0; mi < 4; ++mi) {
      bf16x8 a = *(const bf16x8*)&As[(wave * 64 + mi * 16 + (lane & 15)) * 32 + (lane >> 4) * 8];
      acc[mi][0] = __builtin_amdgcn_mfma_f32_16x16x32_bf16(a, b[0], acc[mi][0], 0, 0, 0);
      acc[mi][1] = __builtin_amdgcn_mfma_f32_16x16x32_bf16(a, b[1], acc[mi][1], 0, 0, 0);
    }
  }
#pragma unroll
  for (int mi = 0; mi < 4; ++mi)
#pragma unroll
    for (int ni = 0; ni < 2; ++ni)
#pragma unroll
      for (int r = 0; r < 4; ++r) {
        int row = m0 + wave * 64 + mi * 16 + (lane >> 4) * 4 + r;
        int col = ni * 16 + (lane & 15);
        tpart[((size_t)ks * M_TOK + row) * RANK + col] = acc[mi][ni][r];
      }
}

__global__ void k_reduce_T(const float* __restrict__ tpart, u16* __restrict__ t32) {
  int idx = blockIdx.x * blockDim.x + threadIdx.x;
  if (idx >= M_TOK * RANK) return;
  int t = idx >> 5, r = idx & 31;
  float v = 0.f;
#pragma unroll
  for (int s = 0; s < 8; ++s) v += tpart[((size_t)s * M_TOK + t) * RANK + r];
  t32[idx] = f2bf(v);
}

// ---------- main GEMM: 256x256, BK=32, ring-4 LDS, FULL-tile frag read-ahead ----------
// R6 skeleton (0-conflict swizzle, W4 + 1 barrier/tile) but ALL 12 fragments
// of tile t+1 (a0[4], a1[4], b[4]) are pre-read at the end of tile t, into the
// SAME registers (dead after the burst -> no ping-pong). Each tile is then one
// dependency-free 32-MFMA burst opening immediately post-barrier; the 12
// ds_reads + 4 gload_lds overlap the co-resident wave's burst.
// Race-safety (as R6): W4 => per-wave stages <=t+2 landed; BARR(t-1) makes
// tile t+1 globally landed before any pre-barrier READN of slot t+1.
__global__ __launch_bounds__(512, 2) void k_gemm8(const u16* __restrict__ xb,
                                                  const u16* __restrict__ wb,
                                                  const u16* __restrict__ t32,
                                                  const u16* __restrict__ a32,
                                                  const float* __restrict__ scale,
                                                  const float* __restrict__ bias,
                                                  float* __restrict__ out) {
  __shared__ u16 As[4][8192];  // 4 slots x 16KB
  __shared__ u16 Bs[4][8192];
  const int tid = threadIdx.x;
  const int l = tid & 63, w = tid >> 6;
  const int wm = w >> 2, wn = w & 3;
  const int bid = blockIdx.x;
  const int swz = (bid & 7) * 64 + (bid >> 3);
  const int m0 = (swz >> 4) * 256, n0 = (swz & 15) * 256;

  const int srow0 = (w * 2 + 0) * 16 + (l >> 2);
  const int srow1 = (w * 2 + 1) * 16 + (l >> 2);
  const int scx = ((l & 3) ^ ((l >> 3) & 3)) * 8;
  const int ldst0 = (w * 2 + 0) * 512 + l * 8;
  const int ldst1 = (w * 2 + 1) * 512 + l * 8;
  const int r15 = l & 15;
  const int cxr = (((l >> 4) ^ ((r15 >> 1) & 3)) * 8);

  f32x4 acc[8][4] = {};

  u16* AsF = &As[0][0];
  u16* BsF = &Bs[0][0];
  const u16* axs0 = xb + (size_t)(m0 + srow0) * K_IN + scx;
  const u16* axs1 = xb + (size_t)(m0 + srow1) * K_IN + scx;
  const u16* bxs0 = wb + (size_t)(n0 + srow0) * K_IN + scx;
  const u16* bxs1 = wb + (size_t)(n0 + srow1) * K_IN + scx;

  // prologue: stage tiles 0,1,2
#pragma unroll
  for (int ts = 0; ts < 3; ++ts) {
    GLOAD_LDS16(axs0 + ts * 32, AsF + ts * 8192 + ldst0);
    GLOAD_LDS16(axs1 + ts * 32, AsF + ts * 8192 + ldst1);
    GLOAD_LDS16(bxs0 + ts * 32, BsF + ts * 8192 + ldst0);
    GLOAD_LDS16(bxs1 + ts * 32, BsF + ts * 8192 + ldst1);
  }
  asm volatile("s_waitcnt vmcnt(4)" ::: "memory");  // tiles 0,1 landed (this wave)
  asm volatile("s_barrier" ::: "memory");           // => landed cross-wave

  const int abase = (wm * 128 + r15) * 32 + cxr;
  const int bbase = (wn * 64 + r15) * 32 + cxr;

  // running stage pointers -> tile 3
  const u16* ap0 = axs0 + 96;
  const u16* ap1 = axs1 + 96;
  const u16* bp0 = bxs0 + 96;
  const u16* bp1 = bxs1 + 96;

  bf16x8 fa0[4], fa1[4], fb[4];  // single frag set, rewritten each tile

#define SA(DST)                                                                     \
  { GLOAD_LDS16(ap0, AsF + (DST) * 8192 + ldst0);                                   \
    GLOAD_LDS16(ap1, AsF + (DST) * 8192 + ldst1);                                   \
    ap0 += 32; ap1 += 32; }
#define SB(DST)                                                                     \
  { GLOAD_LDS16(bp0, BsF + (DST) * 8192 + ldst0);                                   \
    GLOAD_LDS16(bp1, BsF + (DST) * 8192 + ldst1);                                   \
    bp0 += 32; bp1 += 32; }
#define W4  asm volatile("s_waitcnt vmcnt(4)" ::: "memory");
#define W0  asm volatile("s_waitcnt vmcnt(0)" ::: "memory");
#define BARR asm volatile("s_barrier" ::: "memory");
#define READN(NS)                                                                   \
  { const u16* An = AsF + (NS) * 8192;                                              \
    const u16* Bn = BsF + (NS) * 8192;                                              \
    _Pragma("unroll") for (int mi = 0; mi < 4; ++mi)                                \
        fa0[mi] = *(const bf16x8*)&An[abase + mi * 512];                            \
    _Pragma("unroll") for (int mi = 0; mi < 4; ++mi)                                \
        fa1[mi] = *(const bf16x8*)&An[abase + 2048 + mi * 512];                     \
    _Pragma("unroll") for (int nj = 0; nj < 4; ++nj)                                \
        fb[nj] = *(const bf16x8*)&Bn[bbase + nj * 512]; }

// One tile: stages issue first (3-tile slack), then the dependency-free
// 32-MFMA burst, then WAIT + next-tile frag pre-read + trailing barrier.
#define TILE(STAGE, WAIT, RD, BAR)                                                  \
  {                                                                                 \
    STAGE                                                                           \
    __builtin_amdgcn_s_setprio(1);                                                  \
    _Pragma("unroll") for (int mi = 0; mi < 4; ++mi)                                \
    _Pragma("unroll") for (int nj = 0; nj < 4; ++nj)                                \
        acc[mi][nj] =                                                               \
            __builtin_amdgcn_mfma_f32_16x16x32_bf16(fa0[mi], fb[nj], acc[mi][nj], 0, 0, 0); \
    _Pragma("unroll") for (int mi = 0; mi < 4; ++mi)                                \
    _Pragma("unroll") for (int nj = 0; nj < 4; ++nj)                                \
        acc[4 + mi][nj] =                                                           \
            __builtin_amdgcn_mfma_f32_16x16x32_bf16(fa1[mi], fb[nj], acc[4 + mi][nj], 0, 0, 0); \
    __builtin_amdgcn_s_setprio(0);                                                  \
    WAIT                                                                            \
    RD                                                                              \
    BAR                                                                             \
  }

  READN(0)  // tile 0 frags (post-prologue-barrier: globally landed)

  // main loop: tiles 0..123, staging 3..127
#pragma unroll 1
  for (int t = 0; t < 124; t += 4) {
    TILE(SA(3) SB(3), W4, READN(1), BARR)
    TILE(SA(0) SB(0), W4, READN(2), BARR)
    TILE(SA(1) SB(1), W4, READN(3), BARR)
    TILE(SA(2) SB(2), W4, READN(0), BARR)
  }
  // t=124: stage tile 127 -> slot 3
  TILE(SA(3) SB(3), W4, READN(1), BARR)
  // t=125: stage LoRA tile (128) -> slot 0
  {
    const u16* la0 = t32 + (size_t)(m0 + srow0) * RANK + scx;
    const u16* la1 = t32 + (size_t)(m0 + srow1) * RANK + scx;
    const u16* lb0 = a32 + (size_t)(n0 + srow0) * RANK + scx;
    const u16* lb1 = a32 + (size_t)(n0 + srow1) * RANK + scx;
    TILE({ GLOAD_LDS16(la0, AsF + 0 * 8192 + ldst0); GLOAD_LDS16(la1, AsF + 0 * 8192 + ldst1);
           GLOAD_LDS16(lb0, BsF + 0 * 8192 + ldst0); GLOAD_LDS16(lb1, BsF + 0 * 8192 + ldst1); },
         W4, READN(2), BARR)
  }
  // t=126: full drain so LoRA slot is globally landed after this barrier
  TILE(, W0, READN(3), BARR)
  // t=127: nothing outstanding; pre-read LoRA frags (slot 0)
  TILE(, , READN(0), BARR)
  // t=128: LoRA tile, frags preloaded
  TILE(, , , )

  // epilogue: out = acc*scale[col] + bias[col]
#pragma unroll
  for (int nj = 0; nj < 4; ++nj) {
    int col = n0 + wn * 64 + nj * 16 + r15;
    float s = scale[col], bv = bias[col];
#pragma unroll
    for (int fi = 0; fi < 8; ++fi) {
      int row = m0 + wm * 128 + (fi >> 2) * 64 + (fi & 3) * 16 + (l >> 4) * 4;
#pragma unroll
      for (int r = 0; r < 4; ++r)
        out[(size_t)(row + r) * N_OUT + col] = acc[fi][nj][r] * s + bv;
    }
  }
}

// ---------- launch ----------
extern "C" void kernel_launch(void* const* d_in, const int* in_sizes, int n_in,
                              void* d_out, int out_size, void* d_ws, size_t ws_size,
                              hipStream_t stream) {
  const float* x     = (const float*)d_in[0];
  const void*  wq    = d_in[1];
  const float* scale = (const float*)d_in[2];
  const float* loraA = (const float*)d_in[3];
  const float* loraB = (const float*)d_in[4];
  const float* bias  = (const float*)d_in[5];
  float* out = (float*)d_out;

  char* ws = (char*)d_ws;
  u16*   xb    = (u16*)(ws + WS_XB);
  u16*   wbuf  = (u16*)(ws + WS_WB);
  u16*   bb    = (u16*)(ws + WS_BB);
  u16*   a32   = (u16*)(ws + WS_A32);
  u16*   t32   = (u16*)(ws + WS_T32);
  float* tpart = (float*)(ws + WS_TPART);
  int*   flag  = (int*)(ws + WS_FLAG);

  k_convert_x<<<2048, 256, 0, stream>>>((const float4*)x, (ushort4*)xb, M_TOK * K_IN / 4);
  k_detect_wtype<<<1, 64, 0, stream>>>((const int*)wq, flag);
  k_convert_w<<<2048, 256, 0, stream>>>(wq, flag, (ushort4*)wbuf, N_OUT * K_IN / 4);
  k_prep_B<<<512, 256, 0, stream>>>(loraB, bb);
  k_prep_A<<<512, 256, 0, stream>>>(loraA, scale, a32);
  k_lora_T<<<256, 256, 0, stream>>>(xb, bb, tpart);
  k_reduce_T<<<1024, 256, 0, stream>>>(tpart, t32);
  k_gemm8<<<512, 512, 0, stream>>>(xb, wbuf, t32, a32, scale, bias, out);

  (void)in_sizes; (void)n_in; (void)out_size; (void)ws_size;
}